// Round 16
// baseline (60.693 us; speedup 1.0000x reference)
//
#include <hip/hip_runtime.h>
#include <cstddef>
#include <cstdint>
#include <cmath>

#define BB 8
#define TT 24
#define NN 1024
#define FF 3
#define HH 256
#define PP 12
#define RTOT (BB*TT*NN)   // 196608
#define LOG2E 1.4426950408889634f

// raw v_exp_f32 — safe: all softmax-score inputs far from subnormal range.
#define EXP2R(x) __builtin_amdgcn_exp2f(x)

// async global->LDS DMA, 16B per lane: lds dest = base + lane*16 (wave-uniform base)
__device__ __forceinline__ void glds16(const float* __restrict__ g, float* l){
  __builtin_amdgcn_global_load_lds(
      (const __attribute__((address_space(1))) unsigned int*)g,
      (__attribute__((address_space(3))) unsigned int*)l,
      16, 0, 0);
}

// ---- ws float offsets ----
#define TAB_A    0      // 9: spatial A (x 1/16, natural scale)
#define TAB_G    12     // 3: spatial g (x 1/16, natural scale)
#define TAB_AHD  16     // 72: temporal A_hd (x log2e/sqrt32)
#define TAB_UHD  96     // 24: temporal u_hd (x log2e/sqrt32)
#define TAB_VO2  128    // 24x256: Vo @ w_g1^T
#define TAB_C2   6272   // 256
#define P1OFF    8192   // 3x256
#define P2OFF    8960   // 3x256
#define WBOFF    9728   // 256
#define QHOFF    9984   // 3x256
#define KHOFF    10752  // 3x256
#define VHOFF    11520  // 3x256
#define CQOFF    12288  // 256
#define CVOFF    12544  // 256
#define VO1OFF   12800  // 24x256
#define CO1OFF   18944  // 256
#define YSPOFF   19456  // 196608*3 = 589824
#define WG2TOFF  609280 // 256x256 transposed w_g2 (end 674816 ~2.7MB)

// ---------- k_pre: blocks 0-7 = {w_s1,w_s2} proj; 8-19 = w_qkv proj;
//                   blocks 20-35 = coalesced w_g2 transpose ----------
__global__ __launch_bounds__(256) void k_pre(const float* __restrict__ w_s1,
                                             const float* __restrict__ w_s2,
                                             const float* __restrict__ w_qkv,
                                             const float* __restrict__ b_qkv,
                                             const float* __restrict__ w_in,
                                             const float* __restrict__ b_in,
                                             const float* __restrict__ w_g2,
                                             float* __restrict__ ws){
  __shared__ float swin[768], sbin[256];
  __shared__ float tile[256][17];   // transpose tile (pad -> conflict-free)
  const int tid = threadIdx.x;
  if(blockIdx.x >= 20){
    // ---- coalesced transpose: wT[k][c] = w_g2[c][k], k in [t*16, t*16+16)
    const int t = blockIdx.x - 20;
    float* wT = ws + WG2TOFF;
    {
      const int c0 = tid >> 2;          // 0..63
      const int kq = (tid & 3) * 4;     // 0,4,8,12
      #pragma unroll
      for(int pass=0; pass<4; ++pass){
        const int c = pass*64 + c0;
        const float4 v = *(const float4*)&w_g2[(size_t)c*HH + t*16 + kq];
        tile[c][kq+0]=v.x; tile[c][kq+1]=v.y; tile[c][kq+2]=v.z; tile[c][kq+3]=v.w;
      }
    }
    __syncthreads();
    #pragma unroll
    for(int kk=0; kk<16; ++kk)
      wT[(size_t)(t*16+kk)*256 + tid] = tile[tid][kk];
    return;
  }
  swin[tid] = w_in[tid]; swin[256+tid] = w_in[256+tid]; swin[512+tid] = w_in[512+tid];
  sbin[tid] = b_in[tid];
  __syncthreads();
  const int p = tid & 3;
  const bool isS = blockIdx.x < 8;
  const int r = (isS ? blockIdx.x : (blockIdx.x-8))*64 + (tid>>2);
  const float* row;
  if(isS) row = (r < 256) ? (w_s1 + (size_t)r*HH) : (w_s2 + (size_t)(r-256)*HH);
  else    row = w_qkv + (size_t)r*HH;
  float p0=0.f,p1=0.f,p2=0.f,wb=0.f;
  #pragma unroll 4
  for(int c4=0;c4<16;++c4){
    const int i0 = p*64 + c4*4;
    const float4 v = *(const float4*)&row[i0];
    p0=fmaf(v.x,swin[i0*3+0],p0); p1=fmaf(v.x,swin[i0*3+1],p1); p2=fmaf(v.x,swin[i0*3+2],p2); wb=fmaf(v.x,sbin[i0],wb);
    p0=fmaf(v.y,swin[i0*3+3],p0); p1=fmaf(v.y,swin[i0*3+4],p1); p2=fmaf(v.y,swin[i0*3+5],p2); wb=fmaf(v.y,sbin[i0+1],wb);
    p0=fmaf(v.z,swin[i0*3+6],p0); p1=fmaf(v.z,swin[i0*3+7],p1); p2=fmaf(v.z,swin[i0*3+8],p2); wb=fmaf(v.z,sbin[i0+2],wb);
    p0=fmaf(v.w,swin[i0*3+9],p0); p1=fmaf(v.w,swin[i0*3+10],p1);p2=fmaf(v.w,swin[i0*3+11],p2);wb=fmaf(v.w,sbin[i0+3],wb);
  }
  p0 += __shfl_xor(p0,1); p0 += __shfl_xor(p0,2);
  p1 += __shfl_xor(p1,1); p1 += __shfl_xor(p1,2);
  p2 += __shfl_xor(p2,1); p2 += __shfl_xor(p2,2);
  wb += __shfl_xor(wb,1); wb += __shfl_xor(wb,2);
  if(p==0){
    if(isS){
      if(r < 256){
        ws[P1OFF + 0*256 + r] = p0; ws[P1OFF + 1*256 + r] = p1; ws[P1OFF + 2*256 + r] = p2;
        ws[WBOFF + r] = wb;
      } else {
        const int c = r-256;
        ws[P2OFF + 0*256 + c] = p0; ws[P2OFF + 1*256 + c] = p1; ws[P2OFF + 2*256 + c] = p2;
      }
    } else {
      if(r < 256){
        ws[QHOFF + 0*256 + r] = p0; ws[QHOFF + 1*256 + r] = p1; ws[QHOFF + 2*256 + r] = p2;
        ws[CQOFF + r] = wb + b_qkv[r];
      } else if(r < 512){
        const int c = r-256;
        ws[KHOFF + 0*256 + c] = p0; ws[KHOFF + 1*256 + c] = p1; ws[KHOFF + 2*256 + c] = p2;
      } else {
        const int c = r-512;
        ws[VHOFF + 0*256 + c] = p0; ws[VHOFF + 1*256 + c] = p1; ws[VHOFF + 2*256 + c] = p2;
        ws[CVOFF + c] = wb + b_qkv[r];
      }
    }
  }
}

// ---------- k_tabvo1: block 0 = score tables; blocks 1-4 = VO1/CO1 ----------
__global__ __launch_bounds__(256) void k_tabvo1(const float* __restrict__ b_s1,
                                                const float* __restrict__ w_o,
                                                const float* __restrict__ b_o,
                                                float* __restrict__ ws){
  __shared__ float s0[768], s1[768], s2[768], s3[768], sb0[256], sb1[256];
  const int tid = threadIdx.x;
  if(blockIdx.x == 0){
    s0[tid]=ws[P1OFF+tid]; s0[256+tid]=ws[P1OFF+256+tid]; s0[512+tid]=ws[P1OFF+512+tid];
    s1[tid]=ws[P2OFF+tid]; s1[256+tid]=ws[P2OFF+256+tid]; s1[512+tid]=ws[P2OFF+512+tid];
    s2[tid]=ws[QHOFF+tid]; s2[256+tid]=ws[QHOFF+256+tid]; s2[512+tid]=ws[QHOFF+512+tid];
    s3[tid]=ws[KHOFF+tid]; s3[256+tid]=ws[KHOFF+256+tid]; s3[512+tid]=ws[KHOFF+512+tid];
    sb0[tid]=b_s1[tid]+ws[WBOFF+tid];
    sb1[tid]=ws[CQOFF+tid];
    __syncthreads();
    const float SC = 0.0625f;
    const float TS = 0.17677669529663687f * LOG2E;
    if(tid < 9){
      const int f = tid/3, g = tid%3;
      float a=0.f;
      for(int c=0;c<256;++c) a = fmaf(s0[f*256+c], s1[g*256+c], a);
      ws[TAB_A+tid] = a*SC;
    } else if(tid >= 12 && tid < 15){
      const int f = tid-12;
      float a=0.f;
      for(int c=0;c<256;++c) a = fmaf(sb0[c], s1[f*256+c], a);
      ws[TAB_G+f] = a*SC;
    } else if(tid >= 32 && tid < 104){
      const int i2 = tid-32;
      const int hd = i2/9, rr = i2%9, f = rr/3, g = rr%3;
      float a=0.f;
      for(int i=0;i<32;++i) a = fmaf(s2[f*256+hd*32+i], s3[g*256+hd*32+i], a);
      ws[TAB_AHD+i2] = a*TS;
    } else if(tid >= 128 && tid < 152){
      const int i2 = tid-128;
      const int hd = i2/3, g = i2%3;
      float a=0.f;
      for(int i=0;i<32;++i) a = fmaf(sb1[hd*32+i], s3[g*256+hd*32+i], a);
      ws[TAB_UHD+i2] = a*TS;
    }
  } else {
    s0[tid]=ws[VHOFF+tid]; s0[256+tid]=ws[VHOFF+256+tid]; s0[512+tid]=ws[VHOFF+512+tid];
    sb0[tid]=ws[CVOFF+tid];
    __syncthreads();
    const int c = (blockIdx.x-1)*64 + (tid>>2);
    const int p = tid & 3;
    float v[6] = {0,0,0,0,0,0};
    float cop = 0.f;
    #pragma unroll 4
    for(int c4=0;c4<16;++c4){
      const int i0 = p*64 + c4*4;
      const float4 w = *(const float4*)&w_o[(size_t)c*HH + i0];
      #pragma unroll
      for(int e=0;e<4;++e){
        const int i = i0+e;
        const float we = (e==0)?w.x:(e==1)?w.y:(e==2)?w.z:w.w;
        const int hl = (i>>5)&1;
        v[hl*3+0] = fmaf(s0[0*256+i], we, v[hl*3+0]);
        v[hl*3+1] = fmaf(s0[1*256+i], we, v[hl*3+1]);
        v[hl*3+2] = fmaf(s0[2*256+i], we, v[hl*3+2]);
        cop = fmaf(sb0[i], we, cop);
      }
    }
    cop += __shfl_xor(cop,1); cop += __shfl_xor(cop,2);
    #pragma unroll
    for(int hl=0; hl<2; ++hl)
      #pragma unroll
      for(int f=0; f<3; ++f)
        ws[VO1OFF + ((2*p+hl)*3+f)*256 + c] = v[hl*3+f];
    if(p==0) ws[CO1OFF + c] = cop + b_o[c];
  }
}

#define RED6(v) { v+=__shfl_xor(v,1); v+=__shfl_xor(v,2); v+=__shfl_xor(v,4); \
                  v+=__shfl_xor(v,8); v+=__shfl_xor(v,16); v+=__shfl_xor(v,32); }

// ---------- k_spatvo: 0..191 spatial Taylor; 192..291 VO2/C2 ----------
__global__ __launch_bounds__(256) void k_spatvo(const float* __restrict__ x,
                                                const float* __restrict__ w_g1,
                                                const float* __restrict__ b_g1,
                                                float* __restrict__ ws,
                                                float* __restrict__ y){
  __shared__ __align__(16) float4 xs[NN];   // 16 KB (spatial)
  __shared__ float red[4][34];
  __shared__ float mom[34];
  __shared__ float srow[256];               // (vo2)
  const int tid = threadIdx.x;
  if(blockIdx.x >= 192){
    const int bid = blockIdx.x - 192;
    const int jj = bid >> 2;
    srow[tid] = (jj < 24) ? ws[VO1OFF + jj*256 + tid] : ws[CO1OFF + tid];
    __syncthreads();
    const int c = (bid & 3)*64 + (tid>>2);
    const int p = tid & 3;
    float a = 0.f;
    #pragma unroll 4
    for(int c4=0;c4<16;++c4){
      const int i0 = p*64 + c4*4;
      const float4 w = *(const float4*)&w_g1[(size_t)c*HH + i0];
      a = fmaf(w.x, srow[i0+0], a);
      a = fmaf(w.y, srow[i0+1], a);
      a = fmaf(w.z, srow[i0+2], a);
      a = fmaf(w.w, srow[i0+3], a);
    }
    a += __shfl_xor(a,1); a += __shfl_xor(a,2);
    if(p==0){
      if(jj < 24) ws[TAB_VO2 + jj*256 + c] = a;
      else        ws[TAB_C2 + c] = a + b_g1[c];
    }
    return;
  }
  const int bt = blockIdx.x;
  {
    const float* xb = x + (size_t)bt*NN*3 + tid*12;
    const float4 A4 = *(const float4*)&xb[0];
    const float4 B4 = *(const float4*)&xb[4];
    const float4 C4 = *(const float4*)&xb[8];
    xs[tid*4+0] = make_float4(A4.x,A4.y,A4.z,0.f);
    xs[tid*4+1] = make_float4(A4.w,B4.x,B4.y,0.f);
    xs[tid*4+2] = make_float4(B4.z,B4.w,C4.x,0.f);
    xs[tid*4+3] = make_float4(C4.y,C4.z,C4.w,0.f);
  }
  __syncthreads();
  float S0=0,S1=0,S2=0,S3=0,S4=0,S5=0,S6=0,S7=0,S8=0,S9=0,S10=0,S11=0,S12=0,
        S13=0,S14=0,S15=0,S16=0,S17=0,S18=0,S19=0,S20=0,S21=0,S22=0,S23=0,
        S24=0,S25=0,S26=0,S27=0,S28=0,S29=0,S30=0,S31=0,S32=0,S33=0;
  #pragma unroll
  for(int r=0;r<4;++r){
    const float4 v = xs[tid + 256*r];
    const float a=v.x, b=v.y, c=v.z;
    const float aa=a*a, ab=a*b, ac=a*c, bb=b*b, bc=b*c, cc=c*c;
    S0+=a; S1+=b; S2+=c;
    S3+=aa; S4+=ab; S5+=ac; S6+=bb; S7+=bc; S8+=cc;
    const float aaa=aa*a, aab=aa*b, aac=aa*c, abb=a*bb, abc=ab*c, acc=a*cc;
    const float bbb=bb*b, bbc=bb*c, bcc=b*cc, ccc=cc*c;
    S9+=aaa; S10+=aab; S11+=aac; S12+=abb; S13+=abc; S14+=acc;
    S15+=bbb; S16+=bbc; S17+=bcc; S18+=ccc;
    S19+=aa*aa; S20+=aaa*b; S21+=aaa*c; S22+=aa*bb; S23+=aab*c; S24+=aa*cc;
    S25+=a*bbb; S26+=abb*c; S27+=ab*cc; S28+=a*ccc;
    S29+=bb*bb; S30+=bbb*c; S31+=bb*cc; S32+=b*ccc; S33+=cc*cc;
  }
  RED6(S0) RED6(S1) RED6(S2) RED6(S3) RED6(S4) RED6(S5) RED6(S6) RED6(S7)
  RED6(S8) RED6(S9) RED6(S10) RED6(S11) RED6(S12) RED6(S13) RED6(S14) RED6(S15)
  RED6(S16) RED6(S17) RED6(S18) RED6(S19) RED6(S20) RED6(S21) RED6(S22) RED6(S23)
  RED6(S24) RED6(S25) RED6(S26) RED6(S27) RED6(S28) RED6(S29) RED6(S30) RED6(S31)
  RED6(S32) RED6(S33)
  const int wv = tid>>6;
  if((tid&63)==0){
    float* rw = &red[wv][0];
    rw[0]=S0; rw[1]=S1; rw[2]=S2; rw[3]=S3; rw[4]=S4; rw[5]=S5; rw[6]=S6; rw[7]=S7;
    rw[8]=S8; rw[9]=S9; rw[10]=S10; rw[11]=S11; rw[12]=S12; rw[13]=S13; rw[14]=S14;
    rw[15]=S15; rw[16]=S16; rw[17]=S17; rw[18]=S18; rw[19]=S19; rw[20]=S20; rw[21]=S21;
    rw[22]=S22; rw[23]=S23; rw[24]=S24; rw[25]=S25; rw[26]=S26; rw[27]=S27; rw[28]=S28;
    rw[29]=S29; rw[30]=S30; rw[31]=S31; rw[32]=S32; rw[33]=S33;
  }
  __syncthreads();
  if(tid < 34) mom[tid] = ((red[0][tid]+red[1][tid])+(red[2][tid]+red[3][tid]));
  __syncthreads();
  const float m0=mom[0], m1=mom[1], m2=mom[2], m3=mom[3], m4=mom[4], m5=mom[5],
              m6=mom[6], m7=mom[7], m8=mom[8], m9=mom[9], m10=mom[10], m11=mom[11],
              m12=mom[12], m13=mom[13], m14=mom[14], m15=mom[15], m16=mom[16],
              m17=mom[17], m18=mom[18], m19=mom[19], m20=mom[20], m21=mom[21],
              m22=mom[22], m23=mom[23], m24=mom[24], m25=mom[25], m26=mom[26],
              m27=mom[27], m28=mom[28], m29=mom[29], m30=mom[30], m31=mom[31],
              m32=mom[32], m33=mom[33];
  const float A0=ws[TAB_A+0], A1=ws[TAB_A+1], A2=ws[TAB_A+2],
              A3=ws[TAB_A+3], A4_=ws[TAB_A+4], A5=ws[TAB_A+5],
              A6=ws[TAB_A+6], A7=ws[TAB_A+7], A8=ws[TAB_A+8];
  const float G0=ws[TAB_G+0], G1=ws[TAB_G+1], G2=ws[TAB_G+2];
  const float THIRD = 0.33333333333333333f;
  #pragma unroll
  for(int r=0;r<4;++r){
    const float4 xq = xs[tid + 256*r];
    const float u = fmaf(A0,xq.x, fmaf(A3,xq.y, fmaf(A6,xq.z, G0)));
    const float v = fmaf(A1,xq.x, fmaf(A4_,xq.y, fmaf(A7,xq.z, G1)));
    const float w = fmaf(A2,xq.x, fmaf(A5,xq.y, fmaf(A8,xq.z, G2)));
    const float p20 = 0.5f*u*u, p21 = u*v, p22 = u*w,
                p23 = 0.5f*v*v, p24 = v*w, p25 = 0.5f*w*w;
    const float ut = u*THIRD, vt = v*THIRD, wt = w*THIRD;
    const float p30 = p20*ut, p31 = p20*v, p32 = p20*w, p33 = p23*u, p34 = p21*w,
                p35 = p25*u, p36 = p23*vt, p37 = p23*w, p38 = p25*v, p39 = p25*wt;
    float D = fmaf(u,m0, fmaf(v,m1, fmaf(w,m2, 1024.f)));
    D = fmaf(p20,m3, fmaf(p21,m4, fmaf(p22,m5, fmaf(p23,m6, fmaf(p24,m7, fmaf(p25,m8, D))))));
    D = fmaf(p30,m9, fmaf(p31,m10, fmaf(p32,m11, fmaf(p33,m12, fmaf(p34,m13,
        fmaf(p35,m14, fmaf(p36,m15, fmaf(p37,m16, fmaf(p38,m17, fmaf(p39,m18, D))))))))));
    float Na = fmaf(u,m3, fmaf(v,m4, fmaf(w,m5, m0)));
    Na = fmaf(p20,m9, fmaf(p21,m10, fmaf(p22,m11, fmaf(p23,m12, fmaf(p24,m13, fmaf(p25,m14, Na))))));
    Na = fmaf(p30,m19, fmaf(p31,m20, fmaf(p32,m21, fmaf(p33,m22, fmaf(p34,m23,
         fmaf(p35,m24, fmaf(p36,m25, fmaf(p37,m26, fmaf(p38,m27, fmaf(p39,m28, Na))))))))));
    float Nb = fmaf(u,m4, fmaf(v,m6, fmaf(w,m7, m1)));
    Nb = fmaf(p20,m10, fmaf(p21,m12, fmaf(p22,m13, fmaf(p23,m15, fmaf(p24,m16, fmaf(p25,m17, Nb))))));
    Nb = fmaf(p30,m20, fmaf(p31,m22, fmaf(p32,m23, fmaf(p33,m25, fmaf(p34,m26,
         fmaf(p35,m27, fmaf(p36,m29, fmaf(p37,m30, fmaf(p38,m31, fmaf(p39,m32, Nb))))))))));
    float Nc = fmaf(u,m5, fmaf(v,m7, fmaf(w,m8, m2)));
    Nc = fmaf(p20,m11, fmaf(p21,m13, fmaf(p22,m14, fmaf(p23,m16, fmaf(p24,m17, fmaf(p25,m18, Nc))))));
    Nc = fmaf(p30,m21, fmaf(p31,m23, fmaf(p32,m24, fmaf(p33,m26, fmaf(p34,m27,
         fmaf(p35,m28, fmaf(p36,m30, fmaf(p37,m31, fmaf(p38,m32, fmaf(p39,m33, Nc))))))))));
    const float ri = 1.f/D;
    const int gq = bt*NN + tid + 256*r;
    y[(size_t)gq*3+0] = Na*ri;
    y[(size_t)gq*3+1] = Nb*ri;
    y[(size_t)gq*3+2] = Nc*ri;
  }
}

// ---------- k_back: temporal attn + g1 + g2 GEMM + out GEMM, fused ----------
// Occupancy fix: 1024 blocks x 8 rows, 256 thr, 40 KB LDS -> 4 blocks/CU
// (was grid-capped at 2). Same r13 DMA double-buffer structure, dims halved.
#define FMS(r, av) \
  acc[r][0]=fmaf(av,b0.x,acc[r][0]); acc[r][1]=fmaf(av,b0.y,acc[r][1]); \
  acc[r][2]=fmaf(av,b0.z,acc[r][2]); acc[r][3]=fmaf(av,b0.w,acc[r][3]); \
  acc[r][4]=fmaf(av,b1.x,acc[r][4]); acc[r][5]=fmaf(av,b1.y,acc[r][5]); \
  acc[r][6]=fmaf(av,b1.z,acc[r][6]); acc[r][7]=fmaf(av,b1.w,acc[r][7]);

__global__ __launch_bounds__(256,4) void k_back(const float* __restrict__ y,
                                                const float* __restrict__ ws,
                                                const float* __restrict__ b_g2,
                                                const float* __restrict__ w_out,
                                                const float* __restrict__ b_out,
                                                float* __restrict__ outp){
  __shared__ __align__(16) float g1s[8*256];   // 8 KB; later g2 (XOR-swizzled)
  __shared__ __align__(16) float BsU[8192];    // 32 KB: dbuf buf0|buf1 (4096 fl each)
  float* sA  = BsU + 4096;        // [96]   (scratch lives in buf1)
  float* sYt = BsU + 4096 + 96;   // [576]  t*24 + bnl*3 + f
  float* sY  = BsU + 4096 + 672;  // [192]  bnl*24 + hd*3 + f
  const int tid = threadIdx.x;
  const int rowb = blockIdx.x*8;
  const int b = rowb >> 10;
  const int n0 = rowb & 1023;
  const float* wT = ws + WG2TOFF;
  // ---- phase A: temporal attention -> sY[8][24]
  if(tid < 72) sA[tid] = ws[TAB_AHD + tid];
  else if(tid < 96) sA[tid] = ws[TAB_UHD + tid - 72];
  #pragma unroll
  for(int rep=0; rep<3; ++rep){
    const int idx = rep*256 + tid;
    if(idx < TT*24){
      const int t = idx/24, wi = idx - t*24;
      sYt[idx] = y[(((size_t)b*TT + t)*NN + n0)*3 + wi];
    }
  }
  __syncthreads();
  if(tid < 64){
    const int bnl = tid >> 3, hd = tid & 7;
    const float yq0 = sYt[(TT-1)*24 + bnl*3 + 0];
    const float yq1 = sYt[(TT-1)*24 + bnl*3 + 1];
    const float yq2 = sYt[(TT-1)*24 + bnl*3 + 2];
    const float z0 = fmaf(yq0,sA[hd*9+0],fmaf(yq1,sA[hd*9+3],fmaf(yq2,sA[hd*9+6], sA[72+hd*3+0])));
    const float z1 = fmaf(yq0,sA[hd*9+1],fmaf(yq1,sA[hd*9+4],fmaf(yq2,sA[hd*9+7], sA[72+hd*3+1])));
    const float z2 = fmaf(yq0,sA[hd*9+2],fmaf(yq1,sA[hd*9+5],fmaf(yq2,sA[hd*9+8], sA[72+hd*3+2])));
    float psum=0.f, Y0=0.f, Y1=0.f, Y2=0.f;
    #pragma unroll
    for(int t=0;t<TT;++t){
      const float y0 = sYt[t*24+bnl*3+0];
      const float y1 = sYt[t*24+bnl*3+1];
      const float y2 = sYt[t*24+bnl*3+2];
      const float p = EXP2R(fmaf(z0,y0,fmaf(z1,y1,z2*y2)));
      psum += p;
      Y0 = fmaf(p,y0,Y0); Y1 = fmaf(p,y1,Y1); Y2 = fmaf(p,y2,Y2);
    }
    const float rinv = 1.f/psum;
    sY[bnl*24 + hd*3 + 0] = Y0*rinv;  // disjoint from sYt
    sY[bnl*24 + hd*3 + 1] = Y1*rinv;
    sY[bnl*24 + hd*3 + 2] = Y2*rinv;
  }
  __syncthreads();
  // ---- phase B: g1s[r][c] = relu(C2[c] + sY[r][:] @ VO2[:,c])
  {
    const int c = tid;
    float vj[24];
    #pragma unroll
    for(int j=0;j<24;++j) vj[j] = ws[TAB_VO2 + j*256 + c];
    const float cc = ws[TAB_C2 + c];
    #pragma unroll
    for(int r=0;r<8;++r){
      float a = cc;
      #pragma unroll
      for(int j=0;j<24;++j) a = fmaf(sY[r*24+j], vj[j], a);
      g1s[r*HH + c] = a>0.f ? a : 0.f;
    }
  }
  // ---- phase C: g2 = relu(g1 @ w_g2^T + b_g2); tx32 x ky4 x ty2(4 rows), acc[4][8]
  const int tx = tid & 31;
  const int ky = (tid >> 5) & 3;
  const int ty = tid >> 7;
  const int kygrp = (tid >> 6) & 1;
  const int wv2 = tid >> 6;          // wave id 0..3
  const int ln  = tid & 63;
  float acc[4][8];
  #pragma unroll
  for(int r=0;r<4;++r)
    #pragma unroll
    for(int c=0;c<8;++c) acc[r][c]=0.f;
  // prologue: DMA-stage kt=0 into buf0 (4 chunks of 1KB per wave)
  #pragma unroll
  for(int i=0;i<4;++i){
    const int chunk = i*4 + wv2;     // 0..15
    glds16(wT + chunk*256 + ln*4, BsU + chunk*256);
  }
  __syncthreads();   // drains DMA (vmcnt) + phase B g1s/sY ordering
  int buf = 0;
  for(int kt=0; kt<16; ++kt){
    if(kt < 15){ // DMA-stage kt+1 into buf^1 (read last iter; barrier passed)
      #pragma unroll
      for(int i=0;i<4;++i){
        const int chunk = i*4 + wv2;
        glds16(wT + (size_t)(kt+1)*4096 + chunk*256 + ln*4,
               BsU + (buf^1)*4096 + chunk*256);
      }
    }
    const float* B = BsU + buf*4096;
    float4 ar[4];
    #pragma unroll
    for(int r=0;r<4;++r)
      ar[r] = *(const float4*)&g1s[(ty*4+r)*HH + kt*16 + ky*4];
    #pragma unroll
    for(int kk=0;kk<4;++kk){
      const int s = ky*4 + kk;
      const float4 b0 = *(const float4*)&B[s*256 + tx*4];
      const float4 b1 = *(const float4*)&B[s*256 + 128 + tx*4];
      #pragma unroll
      for(int r=0;r<4;++r){
        const float av = (kk==0)?ar[r].x:(kk==1)?ar[r].y:(kk==2)?ar[r].z:ar[r].w;
        FMS(r, av)
      }
    }
    __syncthreads();   // drains vmcnt (DMA had full compute phase to land)
    buf ^= 1;
  }
  // ---- ky reduce: shfl pairs within wave, LDS exchange across wave-pairs
  #pragma unroll
  for(int r=0;r<4;++r)
    #pragma unroll
    for(int c=0;c<8;++c) acc[r][c] += __shfl_xor(acc[r][c], 32);
  float* scr = BsU;   // buf0 as scratch (all reads done after final barrier)
  if(kygrp==1 && (tid&32)==0){
    #pragma unroll
    for(int r=0;r<4;++r){
      const int row = ty*4 + r;
      float4 lo, hi;
      lo.x=acc[r][0]; lo.y=acc[r][1]; lo.z=acc[r][2]; lo.w=acc[r][3];
      hi.x=acc[r][4]; hi.y=acc[r][5]; hi.z=acc[r][6]; hi.w=acc[r][7];
      *(float4*)&scr[row*256 + tx*4] = lo;
      *(float4*)&scr[row*256 + 128 + tx*4] = hi;
    }
  }
  __syncthreads();
  if(kygrp==0 && (tid&32)==0){
    const float4 bg0 = *(const float4*)&b_g2[tx*4];
    const float4 bg1 = *(const float4*)&b_g2[128 + tx*4];
    #pragma unroll
    for(int r=0;r<4;++r){
      const int row = ty*4 + r;
      const float4 lo = *(const float4*)&scr[row*256 + tx*4];
      const float4 hi = *(const float4*)&scr[row*256 + 128 + tx*4];
      float v0 = acc[r][0]+lo.x+bg0.x, v1 = acc[r][1]+lo.y+bg0.y;
      float v2 = acc[r][2]+lo.z+bg0.z, v3 = acc[r][3]+lo.w+bg0.w;
      float v4 = acc[r][4]+hi.x+bg1.x, v5 = acc[r][5]+hi.y+bg1.y;
      float v6 = acc[r][6]+hi.z+bg1.z, v7 = acc[r][7]+hi.w+bg1.w;
      v0 = v0>0.f?v0:0.f; v1 = v1>0.f?v1:0.f; v2 = v2>0.f?v2:0.f; v3 = v3>0.f?v3:0.f;
      v4 = v4>0.f?v4:0.f; v5 = v5>0.f?v5:0.f; v6 = v6>0.f?v6:0.f; v7 = v7>0.f?v7:0.f;
      const int swz = (row & 7) << 2;
      float4 w0, w1;
      w0.x=v0; w0.y=v1; w0.z=v2; w0.w=v3;
      w1.x=v4; w1.y=v5; w1.z=v6; w1.w=v7;
      *(float4*)&g1s[row*HH + ((tx*4      ) ^ swz)] = w0;
      *(float4*)&g1s[row*HH + ((128 + tx*4) ^ swz)] = w1;
    }
  }
  __syncthreads();
  // ---- phase D: out = g2 @ w_out^T + b_out (w_out direct: L1-broadcast loads)
  {
    const int r2 = tid & 7;
    const int jg = tid >> 3;                  // 0..31
    const int swz2 = (r2 & 7) << 2;
    const int bn = rowb + r2;
    const int b2 = bn >> 10, n2 = bn & 1023;
    const bool has2 = (jg < 4);
    const int c2i = has2 ? (jg+32) : 35;
    float a0 = b_out[jg];
    float a1 = b_out[c2i];
    #pragma unroll 4
    for(int k4=0;k4<64;++k4){
      const float4 g4 = *(const float4*)&g1s[r2*HH + ((k4*4) ^ swz2)];
      const float4 wa = *(const float4*)&w_out[(size_t)jg*HH + k4*4];
      const float4 wc = *(const float4*)&w_out[(size_t)c2i*HH + k4*4];
      a0 = fmaf(g4.x,wa.x,fmaf(g4.y,wa.y,fmaf(g4.z,wa.z,fmaf(g4.w,wa.w,a0))));
      a1 = fmaf(g4.x,wc.x,fmaf(g4.y,wc.y,fmaf(g4.z,wc.z,fmaf(g4.w,wc.w,a1))));
    }
    {
      int col = jg;
      int p = col/3, f = col - p*3;
      outp[(size_t)(((b2*PP + p)*NN + n2)*FF + f)] = a0;
      if(has2){
        col = jg+32; p = col/3; f = col - p*3;
        outp[(size_t)(((b2*PP + p)*NN + n2)*FF + f)] = a1;
      }
    }
  }
}

extern "C" void kernel_launch(void* const* d_in, const int* in_sizes, int n_in,
                              void* d_out, int out_size, void* d_ws, size_t ws_size,
                              hipStream_t stream){
  (void)in_sizes; (void)n_in; (void)out_size; (void)ws_size;
  const float* x     = (const float*)d_in[0];
  const float* w_in  = (const float*)d_in[2];
  const float* b_in  = (const float*)d_in[3];
  const float* w_s1  = (const float*)d_in[4];
  const float* b_s1  = (const float*)d_in[5];
  const float* w_s2  = (const float*)d_in[6];
  const float* w_qkv = (const float*)d_in[8];
  const float* b_qkv = (const float*)d_in[9];
  const float* w_o   = (const float*)d_in[10];
  const float* b_o   = (const float*)d_in[11];
  const float* w_g1  = (const float*)d_in[12];
  const float* b_g1  = (const float*)d_in[13];
  const float* w_g2  = (const float*)d_in[14];
  const float* b_g2  = (const float*)d_in[15];
  const float* w_out = (const float*)d_in[16];
  const float* b_out = (const float*)d_in[17];
  float* ws = (float*)d_ws;
  float* y  = ws + YSPOFF;
  float* outp = (float*)d_out;

  k_pre   <<<36,  256, 0, stream>>>(w_s1, w_s2, w_qkv, b_qkv, w_in, b_in, w_g2, ws);
  k_tabvo1<<<5,   256, 0, stream>>>(b_s1, w_o, b_o, ws);
  k_spatvo<<<292, 256, 0, stream>>>(x, w_g1, b_g1, ws, y);
  k_back  <<<BB*NN/8, 256, 0, stream>>>(y, ws, b_g2, w_out, b_out, outp);
}

// Round 17
// 55.294 us; speedup vs baseline: 1.0976x; 1.0976x over previous
//
#include <hip/hip_runtime.h>
#include <cstddef>
#include <cstdint>
#include <cmath>

#define BB 8
#define TT 24
#define NN 1024
#define FF 3
#define HH 256
#define PP 12
#define RTOT (BB*TT*NN)   // 196608
#define LOG2E 1.4426950408889634f

// raw v_exp_f32 — safe: all softmax-score inputs far from subnormal range.
#define EXP2R(x) __builtin_amdgcn_exp2f(x)

// async global->LDS DMA, 16B per lane: lds dest = base + lane*16 (wave-uniform base)
__device__ __forceinline__ void glds16(const float* __restrict__ g, float* l){
  __builtin_amdgcn_global_load_lds(
      (const __attribute__((address_space(1))) unsigned int*)g,
      (__attribute__((address_space(3))) unsigned int*)l,
      16, 0, 0);
}

// ---- ws float offsets ----
#define TAB_A    0      // 9: spatial A (x 1/16, natural scale)
#define TAB_G    12     // 3: spatial g (x 1/16, natural scale)
#define TAB_AHD  16     // 72: temporal A_hd (x log2e/sqrt32)
#define TAB_UHD  96     // 24: temporal u_hd (x log2e/sqrt32)
#define TAB_VO2  128    // 24x256: Vo @ w_g1^T
#define TAB_C2   6272   // 256
#define P1OFF    8192   // 3x256
#define P2OFF    8960   // 3x256
#define WBOFF    9728   // 256
#define QHOFF    9984   // 3x256
#define KHOFF    10752  // 3x256
#define VHOFF    11520  // 3x256
#define CQOFF    12288  // 256
#define CVOFF    12544  // 256
#define VO1OFF   12800  // 24x256
#define CO1OFF   18944  // 256
#define YSPOFF   19456  // 196608*3 = 589824
#define WG2TOFF  609280 // 256x256 transposed w_g2 (end 674816 ~2.7MB)

// ---------- k_pre: blocks 0-7 = {w_s1,w_s2} proj; 8-19 = w_qkv proj;
//                   blocks 20-35 = coalesced w_g2 transpose ----------
__global__ __launch_bounds__(256) void k_pre(const float* __restrict__ w_s1,
                                             const float* __restrict__ w_s2,
                                             const float* __restrict__ w_qkv,
                                             const float* __restrict__ b_qkv,
                                             const float* __restrict__ w_in,
                                             const float* __restrict__ b_in,
                                             const float* __restrict__ w_g2,
                                             float* __restrict__ ws){
  __shared__ float swin[768], sbin[256];
  __shared__ float tile[256][17];   // transpose tile (pad -> conflict-free)
  const int tid = threadIdx.x;
  if(blockIdx.x >= 20){
    // ---- coalesced transpose: wT[k][c] = w_g2[c][k], k in [t*16, t*16+16)
    const int t = blockIdx.x - 20;
    float* wT = ws + WG2TOFF;
    {
      const int c0 = tid >> 2;          // 0..63
      const int kq = (tid & 3) * 4;     // 0,4,8,12
      #pragma unroll
      for(int pass=0; pass<4; ++pass){
        const int c = pass*64 + c0;
        const float4 v = *(const float4*)&w_g2[(size_t)c*HH + t*16 + kq];
        tile[c][kq+0]=v.x; tile[c][kq+1]=v.y; tile[c][kq+2]=v.z; tile[c][kq+3]=v.w;
      }
    }
    __syncthreads();
    #pragma unroll
    for(int kk=0; kk<16; ++kk)
      wT[(size_t)(t*16+kk)*256 + tid] = tile[tid][kk];
    return;
  }
  swin[tid] = w_in[tid]; swin[256+tid] = w_in[256+tid]; swin[512+tid] = w_in[512+tid];
  sbin[tid] = b_in[tid];
  __syncthreads();
  const int p = tid & 3;
  const bool isS = blockIdx.x < 8;
  const int r = (isS ? blockIdx.x : (blockIdx.x-8))*64 + (tid>>2);
  const float* row;
  if(isS) row = (r < 256) ? (w_s1 + (size_t)r*HH) : (w_s2 + (size_t)(r-256)*HH);
  else    row = w_qkv + (size_t)r*HH;
  float p0=0.f,p1=0.f,p2=0.f,wb=0.f;
  #pragma unroll 4
  for(int c4=0;c4<16;++c4){
    const int i0 = p*64 + c4*4;
    const float4 v = *(const float4*)&row[i0];
    p0=fmaf(v.x,swin[i0*3+0],p0); p1=fmaf(v.x,swin[i0*3+1],p1); p2=fmaf(v.x,swin[i0*3+2],p2); wb=fmaf(v.x,sbin[i0],wb);
    p0=fmaf(v.y,swin[i0*3+3],p0); p1=fmaf(v.y,swin[i0*3+4],p1); p2=fmaf(v.y,swin[i0*3+5],p2); wb=fmaf(v.y,sbin[i0+1],wb);
    p0=fmaf(v.z,swin[i0*3+6],p0); p1=fmaf(v.z,swin[i0*3+7],p1); p2=fmaf(v.z,swin[i0*3+8],p2); wb=fmaf(v.z,sbin[i0+2],wb);
    p0=fmaf(v.w,swin[i0*3+9],p0); p1=fmaf(v.w,swin[i0*3+10],p1);p2=fmaf(v.w,swin[i0*3+11],p2);wb=fmaf(v.w,sbin[i0+3],wb);
  }
  p0 += __shfl_xor(p0,1); p0 += __shfl_xor(p0,2);
  p1 += __shfl_xor(p1,1); p1 += __shfl_xor(p1,2);
  p2 += __shfl_xor(p2,1); p2 += __shfl_xor(p2,2);
  wb += __shfl_xor(wb,1); wb += __shfl_xor(wb,2);
  if(p==0){
    if(isS){
      if(r < 256){
        ws[P1OFF + 0*256 + r] = p0; ws[P1OFF + 1*256 + r] = p1; ws[P1OFF + 2*256 + r] = p2;
        ws[WBOFF + r] = wb;
      } else {
        const int c = r-256;
        ws[P2OFF + 0*256 + c] = p0; ws[P2OFF + 1*256 + c] = p1; ws[P2OFF + 2*256 + c] = p2;
      }
    } else {
      if(r < 256){
        ws[QHOFF + 0*256 + r] = p0; ws[QHOFF + 1*256 + r] = p1; ws[QHOFF + 2*256 + r] = p2;
        ws[CQOFF + r] = wb + b_qkv[r];
      } else if(r < 512){
        const int c = r-256;
        ws[KHOFF + 0*256 + c] = p0; ws[KHOFF + 1*256 + c] = p1; ws[KHOFF + 2*256 + c] = p2;
      } else {
        const int c = r-512;
        ws[VHOFF + 0*256 + c] = p0; ws[VHOFF + 1*256 + c] = p1; ws[VHOFF + 2*256 + c] = p2;
        ws[CVOFF + c] = wb + b_qkv[r];
      }
    }
  }
}

// ---------- k_tabvo1: block 0 = score tables; blocks 1-4 = VO1/CO1 ----------
__global__ __launch_bounds__(256) void k_tabvo1(const float* __restrict__ b_s1,
                                                const float* __restrict__ w_o,
                                                const float* __restrict__ b_o,
                                                float* __restrict__ ws){
  __shared__ float s0[768], s1[768], s2[768], s3[768], sb0[256], sb1[256];
  const int tid = threadIdx.x;
  if(blockIdx.x == 0){
    s0[tid]=ws[P1OFF+tid]; s0[256+tid]=ws[P1OFF+256+tid]; s0[512+tid]=ws[P1OFF+512+tid];
    s1[tid]=ws[P2OFF+tid]; s1[256+tid]=ws[P2OFF+256+tid]; s1[512+tid]=ws[P2OFF+512+tid];
    s2[tid]=ws[QHOFF+tid]; s2[256+tid]=ws[QHOFF+256+tid]; s2[512+tid]=ws[QHOFF+512+tid];
    s3[tid]=ws[KHOFF+tid]; s3[256+tid]=ws[KHOFF+256+tid]; s3[512+tid]=ws[KHOFF+512+tid];
    sb0[tid]=b_s1[tid]+ws[WBOFF+tid];
    sb1[tid]=ws[CQOFF+tid];
    __syncthreads();
    const float SC = 0.0625f;
    const float TS = 0.17677669529663687f * LOG2E;
    if(tid < 9){
      const int f = tid/3, g = tid%3;
      float a=0.f;
      for(int c=0;c<256;++c) a = fmaf(s0[f*256+c], s1[g*256+c], a);
      ws[TAB_A+tid] = a*SC;
    } else if(tid >= 12 && tid < 15){
      const int f = tid-12;
      float a=0.f;
      for(int c=0;c<256;++c) a = fmaf(sb0[c], s1[f*256+c], a);
      ws[TAB_G+f] = a*SC;
    } else if(tid >= 32 && tid < 104){
      const int i2 = tid-32;
      const int hd = i2/9, rr = i2%9, f = rr/3, g = rr%3;
      float a=0.f;
      for(int i=0;i<32;++i) a = fmaf(s2[f*256+hd*32+i], s3[g*256+hd*32+i], a);
      ws[TAB_AHD+i2] = a*TS;
    } else if(tid >= 128 && tid < 152){
      const int i2 = tid-128;
      const int hd = i2/3, g = i2%3;
      float a=0.f;
      for(int i=0;i<32;++i) a = fmaf(sb1[hd*32+i], s3[g*256+hd*32+i], a);
      ws[TAB_UHD+i2] = a*TS;
    }
  } else {
    s0[tid]=ws[VHOFF+tid]; s0[256+tid]=ws[VHOFF+256+tid]; s0[512+tid]=ws[VHOFF+512+tid];
    sb0[tid]=ws[CVOFF+tid];
    __syncthreads();
    const int c = (blockIdx.x-1)*64 + (tid>>2);
    const int p = tid & 3;
    float v[6] = {0,0,0,0,0,0};
    float cop = 0.f;
    #pragma unroll 4
    for(int c4=0;c4<16;++c4){
      const int i0 = p*64 + c4*4;
      const float4 w = *(const float4*)&w_o[(size_t)c*HH + i0];
      #pragma unroll
      for(int e=0;e<4;++e){
        const int i = i0+e;
        const float we = (e==0)?w.x:(e==1)?w.y:(e==2)?w.z:w.w;
        const int hl = (i>>5)&1;
        v[hl*3+0] = fmaf(s0[0*256+i], we, v[hl*3+0]);
        v[hl*3+1] = fmaf(s0[1*256+i], we, v[hl*3+1]);
        v[hl*3+2] = fmaf(s0[2*256+i], we, v[hl*3+2]);
        cop = fmaf(sb0[i], we, cop);
      }
    }
    cop += __shfl_xor(cop,1); cop += __shfl_xor(cop,2);
    #pragma unroll
    for(int hl=0; hl<2; ++hl)
      #pragma unroll
      for(int f=0; f<3; ++f)
        ws[VO1OFF + ((2*p+hl)*3+f)*256 + c] = v[hl*3+f];
    if(p==0) ws[CO1OFF + c] = cop + b_o[c];
  }
}

#define RED6(v) { v+=__shfl_xor(v,1); v+=__shfl_xor(v,2); v+=__shfl_xor(v,4); \
                  v+=__shfl_xor(v,8); v+=__shfl_xor(v,16); v+=__shfl_xor(v,32); }

// ---------- k_spatvo: 0..191 spatial Taylor; 192..291 VO2/C2 ----------
__global__ __launch_bounds__(256) void k_spatvo(const float* __restrict__ x,
                                                const float* __restrict__ w_g1,
                                                const float* __restrict__ b_g1,
                                                float* __restrict__ ws,
                                                float* __restrict__ y){
  __shared__ __align__(16) float4 xs[NN];   // 16 KB (spatial)
  __shared__ float red[4][34];
  __shared__ float mom[34];
  __shared__ float srow[256];               // (vo2)
  const int tid = threadIdx.x;
  if(blockIdx.x >= 192){
    const int bid = blockIdx.x - 192;
    const int jj = bid >> 2;
    srow[tid] = (jj < 24) ? ws[VO1OFF + jj*256 + tid] : ws[CO1OFF + tid];
    __syncthreads();
    const int c = (bid & 3)*64 + (tid>>2);
    const int p = tid & 3;
    float a = 0.f;
    #pragma unroll 4
    for(int c4=0;c4<16;++c4){
      const int i0 = p*64 + c4*4;
      const float4 w = *(const float4*)&w_g1[(size_t)c*HH + i0];
      a = fmaf(w.x, srow[i0+0], a);
      a = fmaf(w.y, srow[i0+1], a);
      a = fmaf(w.z, srow[i0+2], a);
      a = fmaf(w.w, srow[i0+3], a);
    }
    a += __shfl_xor(a,1); a += __shfl_xor(a,2);
    if(p==0){
      if(jj < 24) ws[TAB_VO2 + jj*256 + c] = a;
      else        ws[TAB_C2 + c] = a + b_g1[c];
    }
    return;
  }
  const int bt = blockIdx.x;
  {
    const float* xb = x + (size_t)bt*NN*3 + tid*12;
    const float4 A4 = *(const float4*)&xb[0];
    const float4 B4 = *(const float4*)&xb[4];
    const float4 C4 = *(const float4*)&xb[8];
    xs[tid*4+0] = make_float4(A4.x,A4.y,A4.z,0.f);
    xs[tid*4+1] = make_float4(A4.w,B4.x,B4.y,0.f);
    xs[tid*4+2] = make_float4(B4.z,B4.w,C4.x,0.f);
    xs[tid*4+3] = make_float4(C4.y,C4.z,C4.w,0.f);
  }
  __syncthreads();
  float S0=0,S1=0,S2=0,S3=0,S4=0,S5=0,S6=0,S7=0,S8=0,S9=0,S10=0,S11=0,S12=0,
        S13=0,S14=0,S15=0,S16=0,S17=0,S18=0,S19=0,S20=0,S21=0,S22=0,S23=0,
        S24=0,S25=0,S26=0,S27=0,S28=0,S29=0,S30=0,S31=0,S32=0,S33=0;
  #pragma unroll
  for(int r=0;r<4;++r){
    const float4 v = xs[tid + 256*r];
    const float a=v.x, b=v.y, c=v.z;
    const float aa=a*a, ab=a*b, ac=a*c, bb=b*b, bc=b*c, cc=c*c;
    S0+=a; S1+=b; S2+=c;
    S3+=aa; S4+=ab; S5+=ac; S6+=bb; S7+=bc; S8+=cc;
    const float aaa=aa*a, aab=aa*b, aac=aa*c, abb=a*bb, abc=ab*c, acc=a*cc;
    const float bbb=bb*b, bbc=bb*c, bcc=b*cc, ccc=cc*c;
    S9+=aaa; S10+=aab; S11+=aac; S12+=abb; S13+=abc; S14+=acc;
    S15+=bbb; S16+=bbc; S17+=bcc; S18+=ccc;
    S19+=aa*aa; S20+=aaa*b; S21+=aaa*c; S22+=aa*bb; S23+=aab*c; S24+=aa*cc;
    S25+=a*bbb; S26+=abb*c; S27+=ab*cc; S28+=a*ccc;
    S29+=bb*bb; S30+=bbb*c; S31+=bb*cc; S32+=b*ccc; S33+=cc*cc;
  }
  RED6(S0) RED6(S1) RED6(S2) RED6(S3) RED6(S4) RED6(S5) RED6(S6) RED6(S7)
  RED6(S8) RED6(S9) RED6(S10) RED6(S11) RED6(S12) RED6(S13) RED6(S14) RED6(S15)
  RED6(S16) RED6(S17) RED6(S18) RED6(S19) RED6(S20) RED6(S21) RED6(S22) RED6(S23)
  RED6(S24) RED6(S25) RED6(S26) RED6(S27) RED6(S28) RED6(S29) RED6(S30) RED6(S31)
  RED6(S32) RED6(S33)
  const int wv = tid>>6;
  if((tid&63)==0){
    float* rw = &red[wv][0];
    rw[0]=S0; rw[1]=S1; rw[2]=S2; rw[3]=S3; rw[4]=S4; rw[5]=S5; rw[6]=S6; rw[7]=S7;
    rw[8]=S8; rw[9]=S9; rw[10]=S10; rw[11]=S11; rw[12]=S12; rw[13]=S13; rw[14]=S14;
    rw[15]=S15; rw[16]=S16; rw[17]=S17; rw[18]=S18; rw[19]=S19; rw[20]=S20; rw[21]=S21;
    rw[22]=S22; rw[23]=S23; rw[24]=S24; rw[25]=S25; rw[26]=S26; rw[27]=S27; rw[28]=S28;
    rw[29]=S29; rw[30]=S30; rw[31]=S31; rw[32]=S32; rw[33]=S33;
  }
  __syncthreads();
  if(tid < 34) mom[tid] = ((red[0][tid]+red[1][tid])+(red[2][tid]+red[3][tid]));
  __syncthreads();
  const float m0=mom[0], m1=mom[1], m2=mom[2], m3=mom[3], m4=mom[4], m5=mom[5],
              m6=mom[6], m7=mom[7], m8=mom[8], m9=mom[9], m10=mom[10], m11=mom[11],
              m12=mom[12], m13=mom[13], m14=mom[14], m15=mom[15], m16=mom[16],
              m17=mom[17], m18=mom[18], m19=mom[19], m20=mom[20], m21=mom[21],
              m22=mom[22], m23=mom[23], m24=mom[24], m25=mom[25], m26=mom[26],
              m27=mom[27], m28=mom[28], m29=mom[29], m30=mom[30], m31=mom[31],
              m32=mom[32], m33=mom[33];
  const float A0=ws[TAB_A+0], A1=ws[TAB_A+1], A2=ws[TAB_A+2],
              A3=ws[TAB_A+3], A4_=ws[TAB_A+4], A5=ws[TAB_A+5],
              A6=ws[TAB_A+6], A7=ws[TAB_A+7], A8=ws[TAB_A+8];
  const float G0=ws[TAB_G+0], G1=ws[TAB_G+1], G2=ws[TAB_G+2];
  const float THIRD = 0.33333333333333333f;
  #pragma unroll
  for(int r=0;r<4;++r){
    const float4 xq = xs[tid + 256*r];
    const float u = fmaf(A0,xq.x, fmaf(A3,xq.y, fmaf(A6,xq.z, G0)));
    const float v = fmaf(A1,xq.x, fmaf(A4_,xq.y, fmaf(A7,xq.z, G1)));
    const float w = fmaf(A2,xq.x, fmaf(A5,xq.y, fmaf(A8,xq.z, G2)));
    const float p20 = 0.5f*u*u, p21 = u*v, p22 = u*w,
                p23 = 0.5f*v*v, p24 = v*w, p25 = 0.5f*w*w;
    const float ut = u*THIRD, vt = v*THIRD, wt = w*THIRD;
    const float p30 = p20*ut, p31 = p20*v, p32 = p20*w, p33 = p23*u, p34 = p21*w,
                p35 = p25*u, p36 = p23*vt, p37 = p23*w, p38 = p25*v, p39 = p25*wt;
    float D = fmaf(u,m0, fmaf(v,m1, fmaf(w,m2, 1024.f)));
    D = fmaf(p20,m3, fmaf(p21,m4, fmaf(p22,m5, fmaf(p23,m6, fmaf(p24,m7, fmaf(p25,m8, D))))));
    D = fmaf(p30,m9, fmaf(p31,m10, fmaf(p32,m11, fmaf(p33,m12, fmaf(p34,m13,
        fmaf(p35,m14, fmaf(p36,m15, fmaf(p37,m16, fmaf(p38,m17, fmaf(p39,m18, D))))))))));
    float Na = fmaf(u,m3, fmaf(v,m4, fmaf(w,m5, m0)));
    Na = fmaf(p20,m9, fmaf(p21,m10, fmaf(p22,m11, fmaf(p23,m12, fmaf(p24,m13, fmaf(p25,m14, Na))))));
    Na = fmaf(p30,m19, fmaf(p31,m20, fmaf(p32,m21, fmaf(p33,m22, fmaf(p34,m23,
         fmaf(p35,m24, fmaf(p36,m25, fmaf(p37,m26, fmaf(p38,m27, fmaf(p39,m28, Na))))))))));
    float Nb = fmaf(u,m4, fmaf(v,m6, fmaf(w,m7, m1)));
    Nb = fmaf(p20,m10, fmaf(p21,m12, fmaf(p22,m13, fmaf(p23,m15, fmaf(p24,m16, fmaf(p25,m17, Nb))))));
    Nb = fmaf(p30,m20, fmaf(p31,m22, fmaf(p32,m23, fmaf(p33,m25, fmaf(p34,m26,
         fmaf(p35,m27, fmaf(p36,m29, fmaf(p37,m30, fmaf(p38,m31, fmaf(p39,m32, Nb))))))))));
    float Nc = fmaf(u,m5, fmaf(v,m7, fmaf(w,m8, m2)));
    Nc = fmaf(p20,m11, fmaf(p21,m13, fmaf(p22,m14, fmaf(p23,m16, fmaf(p24,m17, fmaf(p25,m18, Nc))))));
    Nc = fmaf(p30,m21, fmaf(p31,m23, fmaf(p32,m24, fmaf(p33,m26, fmaf(p34,m27,
         fmaf(p35,m28, fmaf(p36,m30, fmaf(p37,m31, fmaf(p38,m32, fmaf(p39,m33, Nc))))))))));
    const float ri = 1.f/D;
    const int gq = bt*NN + tid + 256*r;
    y[(size_t)gq*3+0] = Na*ri;
    y[(size_t)gq*3+1] = Nb*ri;
    y[(size_t)gq*3+2] = Nc*ri;
  }
}

// ---------- k_back: temporal attn + g1 + g2 GEMM + out GEMM, fused ----------
// r13 structure, ONE change: DMA issue moved AFTER the kk-compute (was before
// the ds_reads, which forced an alias-guard vmcnt(0) drain ahead of compute).
// Order now: ds_read(buf) -> FMA -> DMA(buf^1) -> barrier.
#define FMS(r, av) \
  acc[r][0]=fmaf(av,b0.x,acc[r][0]); acc[r][1]=fmaf(av,b0.y,acc[r][1]); \
  acc[r][2]=fmaf(av,b0.z,acc[r][2]); acc[r][3]=fmaf(av,b0.w,acc[r][3]); \
  acc[r][4]=fmaf(av,b1.x,acc[r][4]); acc[r][5]=fmaf(av,b1.y,acc[r][5]); \
  acc[r][6]=fmaf(av,b1.z,acc[r][6]); acc[r][7]=fmaf(av,b1.w,acc[r][7]);

__global__ __launch_bounds__(256,3) void k_back(const float* __restrict__ y,
                                                const float* __restrict__ ws,
                                                const float* __restrict__ b_g2,
                                                const float* __restrict__ w_out,
                                                const float* __restrict__ b_out,
                                                float* __restrict__ outp){
  __shared__ __align__(16) float g1s[16*256];  // 16 KB; later g2 (XOR-swizzled)
  __shared__ __align__(16) float BsU[8192];    // 32 KB: dbuf buf0|buf1 (4096 fl each)
  float* sA  = BsU + 4096;        // [96]
  float* sYt = BsU + 4096 + 96;   // [1152]  t*48 + bnl*3 + f
  float* sY  = BsU + 4096 + 1248; // [384]   bnl*24 + hd*3 + f
  const int tid = threadIdx.x;
  const int rowb = blockIdx.x*16;
  const int b = rowb >> 10;
  const int n0 = rowb & 1023;
  const float* wT = ws + WG2TOFF;
  // ---- phase A: temporal attention -> sY[16][24]
  if(tid < 72) sA[tid] = ws[TAB_AHD + tid];
  else if(tid < 96) sA[tid] = ws[TAB_UHD + tid - 72];
  #pragma unroll
  for(int rep=0; rep<5; ++rep){
    const int idx = rep*256 + tid;
    if(idx < TT*48){
      const int t = idx/48, wi = idx - t*48;
      sYt[idx] = y[(((size_t)b*TT + t)*NN + n0)*3 + wi];
    }
  }
  __syncthreads();
  if(tid < 128){
    const int bnl = tid >> 3, hd = tid & 7;
    float yt[TT][3];
    #pragma unroll
    for(int t=0;t<TT;++t){
      yt[t][0]=sYt[t*48+bnl*3+0];
      yt[t][1]=sYt[t*48+bnl*3+1];
      yt[t][2]=sYt[t*48+bnl*3+2];
    }
    const float yq0 = yt[TT-1][0], yq1 = yt[TT-1][1], yq2 = yt[TT-1][2];
    const float z0 = fmaf(yq0,sA[hd*9+0],fmaf(yq1,sA[hd*9+3],fmaf(yq2,sA[hd*9+6], sA[72+hd*3+0])));
    const float z1 = fmaf(yq0,sA[hd*9+1],fmaf(yq1,sA[hd*9+4],fmaf(yq2,sA[hd*9+7], sA[72+hd*3+1])));
    const float z2 = fmaf(yq0,sA[hd*9+2],fmaf(yq1,sA[hd*9+5],fmaf(yq2,sA[hd*9+8], sA[72+hd*3+2])));
    float psum=0.f, Y0=0.f, Y1=0.f, Y2=0.f;
    #pragma unroll
    for(int t=0;t<TT;++t){
      const float p = EXP2R(fmaf(z0,yt[t][0],fmaf(z1,yt[t][1],z2*yt[t][2])));
      psum += p;
      Y0 = fmaf(p,yt[t][0],Y0); Y1 = fmaf(p,yt[t][1],Y1); Y2 = fmaf(p,yt[t][2],Y2);
    }
    const float rinv = 1.f/psum;
    sY[bnl*24 + hd*3 + 0] = Y0*rinv;  // disjoint from sYt
    sY[bnl*24 + hd*3 + 1] = Y1*rinv;
    sY[bnl*24 + hd*3 + 2] = Y2*rinv;
  }
  __syncthreads();
  // ---- phase B: g1s[r][c] = relu(C2[c] + sY[r][:] @ VO2[:,c])
  {
    const int c = tid;
    float vj[24];
    #pragma unroll
    for(int j=0;j<24;++j) vj[j] = ws[TAB_VO2 + j*256 + c];
    const float cc = ws[TAB_C2 + c];
    #pragma unroll 4
    for(int r=0;r<16;++r){
      float a = cc;
      #pragma unroll
      for(int j=0;j<24;++j) a = fmaf(sY[r*24+j], vj[j], a);
      g1s[r*HH + c] = a>0.f ? a : 0.f;
    }
  }
  // ---- phase C: g2 = relu(g1 @ w_g2^T + b_g2); tx32 x ky4 x ty2, acc[8][8]
  const int tx = tid & 31;
  const int ky = (tid >> 5) & 3;
  const int ty = tid >> 7;
  const int kygrp = (tid >> 6) & 1;
  const int wv2 = tid >> 6;          // wave id 0..3
  const int ln  = tid & 63;
  float acc[8][8];
  #pragma unroll
  for(int r=0;r<8;++r)
    #pragma unroll
    for(int c=0;c<8;++c) acc[r][c]=0.f;
  // prologue: DMA-stage kt=0 into buf0 (4 chunks of 1KB per wave)
  #pragma unroll
  for(int i=0;i<4;++i){
    const int chunk = i*4 + wv2;     // 0..15
    glds16(wT + chunk*256 + ln*4, BsU + chunk*256);
  }
  __syncthreads();   // drains DMA (vmcnt) + phase B g1s/sY ordering
  int buf = 0;
  for(int kt=0; kt<16; ++kt){
    const float* B = BsU + buf*4096;
    float4 ar[8];
    #pragma unroll
    for(int r=0;r<8;++r)
      ar[r] = *(const float4*)&g1s[(ty*8+r)*HH + kt*16 + ky*4];
    #pragma unroll
    for(int kk=0;kk<4;++kk){
      const int s = ky*4 + kk;
      const float4 b0 = *(const float4*)&B[s*256 + tx*4];
      const float4 b1 = *(const float4*)&B[s*256 + 128 + tx*4];
      #pragma unroll
      for(int r=0;r<8;++r){
        const float av = (kk==0)?ar[r].x:(kk==1)?ar[r].y:(kk==2)?ar[r].z:ar[r].w;
        FMS(r, av)
      }
    }
    if(kt < 15){ // DMA issue AFTER compute: no alias guard ahead of ds_reads;
                 // drain happens at the barrier, overlapped by co-resident block
      #pragma unroll
      for(int i=0;i<4;++i){
        const int chunk = i*4 + wv2;
        glds16(wT + (size_t)(kt+1)*4096 + chunk*256 + ln*4,
               BsU + (buf^1)*4096 + chunk*256);
      }
    }
    __syncthreads();
    buf ^= 1;
  }
  // ---- ky reduce: shfl pairs within wave, LDS exchange across wave-pairs
  #pragma unroll
  for(int r=0;r<8;++r)
    #pragma unroll
    for(int c=0;c<8;++c) acc[r][c] += __shfl_xor(acc[r][c], 32);
  float* scr = BsU;   // buf0 as 16 KB scratch (all reads done after final barrier)
  if(kygrp==1 && (tid&32)==0){
    #pragma unroll
    for(int r=0;r<8;++r){
      const int row = ty*8 + r;
      float4 lo, hi;
      lo.x=acc[r][0]; lo.y=acc[r][1]; lo.z=acc[r][2]; lo.w=acc[r][3];
      hi.x=acc[r][4]; hi.y=acc[r][5]; hi.z=acc[r][6]; hi.w=acc[r][7];
      *(float4*)&scr[row*256 + tx*4] = lo;
      *(float4*)&scr[row*256 + 128 + tx*4] = hi;
    }
  }
  __syncthreads();
  if(kygrp==0 && (tid&32)==0){
    const float4 bg0 = *(const float4*)&b_g2[tx*4];
    const float4 bg1 = *(const float4*)&b_g2[128 + tx*4];
    #pragma unroll
    for(int r=0;r<8;++r){
      const int row = ty*8 + r;
      const float4 lo = *(const float4*)&scr[row*256 + tx*4];
      const float4 hi = *(const float4*)&scr[row*256 + 128 + tx*4];
      float v0 = acc[r][0]+lo.x+bg0.x, v1 = acc[r][1]+lo.y+bg0.y;
      float v2 = acc[r][2]+lo.z+bg0.z, v3 = acc[r][3]+lo.w+bg0.w;
      float v4 = acc[r][4]+hi.x+bg1.x, v5 = acc[r][5]+hi.y+bg1.y;
      float v6 = acc[r][6]+hi.z+bg1.z, v7 = acc[r][7]+hi.w+bg1.w;
      v0 = v0>0.f?v0:0.f; v1 = v1>0.f?v1:0.f; v2 = v2>0.f?v2:0.f; v3 = v3>0.f?v3:0.f;
      v4 = v4>0.f?v4:0.f; v5 = v5>0.f?v5:0.f; v6 = v6>0.f?v6:0.f; v7 = v7>0.f?v7:0.f;
      const int swz = (row & 7) << 2;
      float4 w0, w1;
      w0.x=v0; w0.y=v1; w0.z=v2; w0.w=v3;
      w1.x=v4; w1.y=v5; w1.z=v6; w1.w=v7;
      *(float4*)&g1s[row*HH + ((tx*4      ) ^ swz)] = w0;
      *(float4*)&g1s[row*HH + ((128 + tx*4) ^ swz)] = w1;
    }
  }
  __syncthreads();
  // ---- phase D: out = g2 @ w_out^T + b_out (w_out direct: L1-broadcast loads)
  {
    const int r2 = tid & 15;
    const int jg = tid >> 4;                  // 0..15
    const int swz2 = (r2 & 7) << 2;
    const int bn = rowb + r2;
    const int b2 = bn >> 10, n2 = bn & 1023;
    const bool has3 = (jg < 4);
    const int c2i = has3 ? (jg+32) : 35;
    float a0 = b_out[jg];
    float a1 = b_out[jg+16];
    float a2 = b_out[c2i];
    #pragma unroll 4
    for(int k4=0;k4<64;++k4){
      const float4 g4 = *(const float4*)&g1s[r2*HH + ((k4*4) ^ swz2)];
      const float4 wa = *(const float4*)&w_out[(size_t)(jg   )*HH + k4*4];
      const float4 wb = *(const float4*)&w_out[(size_t)(jg+16)*HH + k4*4];
      const float4 wc = *(const float4*)&w_out[(size_t)c2i*HH + k4*4];
      a0 = fmaf(g4.x,wa.x,fmaf(g4.y,wa.y,fmaf(g4.z,wa.z,fmaf(g4.w,wa.w,a0))));
      a1 = fmaf(g4.x,wb.x,fmaf(g4.y,wb.y,fmaf(g4.z,wb.z,fmaf(g4.w,wb.w,a1))));
      a2 = fmaf(g4.x,wc.x,fmaf(g4.y,wc.y,fmaf(g4.z,wc.z,fmaf(g4.w,wc.w,a2))));
    }
    {
      int col = jg;
      int p = col/3, f = col - p*3;
      outp[(size_t)(((b2*PP + p)*NN + n2)*FF + f)] = a0;
      col = jg+16; p = col/3; f = col - p*3;
      outp[(size_t)(((b2*PP + p)*NN + n2)*FF + f)] = a1;
      if(has3){
        col = jg+32; p = col/3; f = col - p*3;
        outp[(size_t)(((b2*PP + p)*NN + n2)*FF + f)] = a2;
      }
    }
  }
}

extern "C" void kernel_launch(void* const* d_in, const int* in_sizes, int n_in,
                              void* d_out, int out_size, void* d_ws, size_t ws_size,
                              hipStream_t stream){
  (void)in_sizes; (void)n_in; (void)out_size; (void)ws_size;
  const float* x     = (const float*)d_in[0];
  const float* w_in  = (const float*)d_in[2];
  const float* b_in  = (const float*)d_in[3];
  const float* w_s1  = (const float*)d_in[4];
  const float* b_s1  = (const float*)d_in[5];
  const float* w_s2  = (const float*)d_in[6];
  const float* w_qkv = (const float*)d_in[8];
  const float* b_qkv = (const float*)d_in[9];
  const float* w_o   = (const float*)d_in[10];
  const float* b_o   = (const float*)d_in[11];
  const float* w_g1  = (const float*)d_in[12];
  const float* b_g1  = (const float*)d_in[13];
  const float* w_g2  = (const float*)d_in[14];
  const float* b_g2  = (const float*)d_in[15];
  const float* w_out = (const float*)d_in[16];
  const float* b_out = (const float*)d_in[17];
  float* ws = (float*)d_ws;
  float* y  = ws + YSPOFF;
  float* outp = (float*)d_out;

  k_pre   <<<36,  256, 0, stream>>>(w_s1, w_s2, w_qkv, b_qkv, w_in, b_in, w_g2, ws);
  k_tabvo1<<<5,   256, 0, stream>>>(b_s1, w_o, b_o, ws);
  k_spatvo<<<292, 256, 0, stream>>>(x, w_g1, b_g1, ws, y);
  k_back  <<<BB*NN/16, 256, 0, stream>>>(y, ws, b_g2, w_out, b_out, outp);
}